// Round 4
// baseline (307.920 us; speedup 1.0000x reference)
//
#include <hip/hip_runtime.h>
#include <stdint.h>

// Cost volume: out[b,k,h,w] = (1/81) * sum_c x1[b,c,h,w] * x2[b,c,h-i,w-j]
// k = (9i+j) mod 81, i,j in [-4,4], zero-padded x2. B=4 C=128 H=128 W=256 fp32.
//
// Round 4 design — NO LDS, NO barriers:
//  - block = 9 waves (576 thr); wave wv -> displacement row i = wv-4.
//  - tile 8h x 64w; lane owns 8 w-pixels -> acc[9][8] = 72 fp32 regs.
//  - Both inputs read straight from global: per lane per channel
//    2 dwordx4 (x1) + 4 dwordx4 (x2, 16 halo words) feeding 72 FMAs.
//    Reuse is served by L1 (per-channel tile ~7 KB, shared by all 9 waves
//    in natural lockstep), L2 (per-block all-channel set ~850 KB), L3
//    (both inputs = 128 MB < 256 MB).
//  - OOB x2 halo groups are always FULLY oob (groups 16B-aligned, W=256
//    divisible by 4): pointer -> zeroed d_ws, per-channel stride -> 0.
//  - __launch_bounds__(576,1): full register budget. Round-2/3 lesson:
//    9-wave blocks put 3 waves on one SIMD, so minwaves=2 caps the unified
//    file at ~170 regs -> AGPR-split + scratch spill (WRITE_SIZE 53.6 MB
//    vs 41.5 MB output). minwaves=1 -> no spill.

#define HH 128
#define WW 256
#define CCT 128
#define DD 81
#define TH 8
#define TWIDE 64
#define NT 576

__global__ __launch_bounds__(NT, 1) void cost_volume_kernel(
    const float* __restrict__ x1, const float* __restrict__ x2,
    float* __restrict__ out, const float* __restrict__ zws) {
  const int b = blockIdx.z;
  const int h0 = blockIdx.y * TH;
  const int w0 = blockIdx.x * TWIDE;
  const int t = threadIdx.x;
  const int wv = t >> 6;     // 0..8 -> i = wv-4
  const int lane = t & 63;
  const int hl = lane >> 3;  // 0..7 local h row
  const int g = lane & 7;    // 0..7 group of 8 w pixels

  const int h2 = h0 + hl - (wv - 4);  // x2 source row for this wave
  const bool hok = (unsigned)h2 < (unsigned)HH;

  const float* x1b = x1 + (size_t)b * CCT * HH * WW;
  const float* x2b = x2 + (size_t)b * CCT * HH * WW;

  // x1 pointer: always in-bounds
  const float* p1 = x1b + ((size_t)(h0 + hl) << 8) + w0 + g * 8;

  // x2: four 16B groups covering global words w0+8g-4 .. w0+8g+11
  const float* p2[4];
  int s2[4];
#pragma unroll
  for (int q = 0; q < 4; ++q) {
    const int w = w0 + g * 8 - 4 + q * 4;
    const bool ok = hok && (unsigned)w <= (unsigned)(WW - 4);
    p2[q] = ok ? (x2b + ((size_t)h2 << 8) + w) : zws;
    s2[q] = ok ? (HH * WW) : 0;
  }

  float acc[9][8];
#pragma unroll
  for (int jj = 0; jj < 9; ++jj)
#pragma unroll
    for (int p = 0; p < 8; ++p) acc[jj][p] = 0.f;

#pragma unroll 2
  for (int c = 0; c < CCT; ++c) {
    float xv[8], v[16];
    *(float4*)&xv[0] = *(const float4*)(p1);
    *(float4*)&xv[4] = *(const float4*)(p1 + 4);
    *(float4*)&v[0]  = *(const float4*)p2[0];
    *(float4*)&v[4]  = *(const float4*)p2[1];
    *(float4*)&v[8]  = *(const float4*)p2[2];
    *(float4*)&v[12] = *(const float4*)p2[3];
#pragma unroll
    for (int jj = 0; jj < 9; ++jj)
#pragma unroll
      for (int p = 0; p < 8; ++p)
        acc[jj][p] = fmaf(xv[p], v[p + 8 - jj], acc[jj][p]);
    p1 += HH * WW;
#pragma unroll
    for (int q = 0; q < 4; ++q) p2[q] += s2[q];
  }

  // epilogue: kk = (9*(wv-4) + (jj-4)) mod 81 = (9*wv + jj + 41) % 81
  const float s = 1.0f / 81.0f;
#pragma unroll
  for (int jj = 0; jj < 9; ++jj) {
    const int kk = (9 * wv + jj + 41) % 81;
    float* o = out + (((size_t)b * DD + kk) * HH + (h0 + hl)) * WW + w0 + g * 8;
    float4 lo, hi;
    lo.x = acc[jj][0] * s; lo.y = acc[jj][1] * s;
    lo.z = acc[jj][2] * s; lo.w = acc[jj][3] * s;
    hi.x = acc[jj][4] * s; hi.y = acc[jj][5] * s;
    hi.z = acc[jj][6] * s; hi.w = acc[jj][7] * s;
    *(float4*)o = lo;
    *(float4*)(o + 4) = hi;
  }
}

extern "C" void kernel_launch(void* const* d_in, const int* in_sizes, int n_in,
                              void* d_out, int out_size, void* d_ws,
                              size_t ws_size, hipStream_t stream) {
  const float* x1 = (const float*)d_in[0];
  const float* x2 = (const float*)d_in[1];
  float* out = (float*)d_out;

  // zero 256 B of workspace: OOB halo groups read zeros from here
  hipMemsetAsync(d_ws, 0, 256, stream);

  dim3 grid(WW / TWIDE, HH / TH, 4);  // 4 x 16 x 4 = 256 blocks
  dim3 block(NT);
  hipLaunchKernelGGL(cost_volume_kernel, grid, block, 0, stream, x1, x2, out,
                     (const float*)d_ws);
}

// Round 5
// 196.331 us; speedup vs baseline: 1.5684x; 1.5684x over previous
//
#include <hip/hip_runtime.h>
#include <stdint.h>

// Cost volume: out[b,k,h,w] = (1/81) * sum_c x1[b,c,h,w] * x2[b,c,h-i,w-j]
// k = (9i+j) mod 81, i,j in [-4,4], zero-padded x2. B=4 C=128 H=128 W=256 fp32.
//
// Round 5: bf16 MFMA formulation (fp32 VALU is structurally LDS-BW-bound).
// Toeplitz window: D[m][n] = sum_c x1[c, w0+m] * x2[c, h-i, w0-4+n]
//   -> out(w0+m, j) = D[m][m+4-j], window 24 cols = 2x mfma_f32_16x16x32_bf16
//      (tile0 n=0..15, tile1 n=16..23 + 8 junk cols never read).
// Block: 1024 thr = 16 waves = (hl 0..7) x (igrp 0..1); tile 8h x 16w.
//   igrp0: i in {-4..0} (acc 5x2x4=40 fp32), igrp1: i in {1..4} (32).
//   16 waves = exactly 4/SIMD -> 128-reg budget; acc 40 + ~70 work fits
//   WITHOUT spill (R2/R3 failure mode).
// Staging: fp32->bf16 convert + [c][w] -> [w][c] transpose via VALU regs,
//   packed c-pair b32 LDS writes; K-chunks of 32 ch, single 50 KB buffer.
//   LDS layout (bytes): A: [8 hl][16 m][32k*2B +16 pad = 80], row 1296
//                       B: [16 h2][32 wcol][80], row 2576  (strides keep
//   16B alignment for b128 frag reads and +4-bank rotation per row).
// Epilogue: MFMA C-layout (row=quad*4+reg, col=lane&15) scattered -> LDS
//   scratch -> coalesced float4 global stores.

#define HH 128
#define WW 256
#define HW 32768
#define DD 81
#define NT 1024

typedef __attribute__((ext_vector_type(8))) short short8;
typedef __attribute__((ext_vector_type(4))) float float4v;

// LDS geometry in ushorts
#define A_ROW 648          // 16 m * 40 + 8 pad
#define B_ROW 1288         // 32 wcol * 40 + 8 pad
#define KSTR 40            // 32 bf16 + 8 pad ushorts
#define B_BASE 5184        // A region = 8 * 648
#define BUF_USH 25792      // 5184 + 16*1288 = 51584 B total

__device__ __forceinline__ uint32_t f2bf(float f) {
  uint32_t u = __float_as_uint(f);
  return (u + 0x7fffu + ((u >> 16) & 1u)) >> 16;
}

template <int NI, int I0>
__device__ __forceinline__ void compute_chunk(const unsigned short* buf, int hl,
                                              int n16, int quad, float4v* acc0,
                                              float4v* acc1) {
  const short8 a = *(const short8*)(buf + hl * A_ROW + n16 * KSTR + quad * 8);
#pragma unroll
  for (int ii = 0; ii < NI; ++ii) {
    const int row = hl - (I0 + ii) + 4;  // 0..15
    const unsigned short* bp = buf + B_BASE + row * B_ROW + n16 * KSTR + quad * 8;
    const short8 b0 = *(const short8*)(bp);
    const short8 b1 = *(const short8*)(bp + 16 * KSTR);
    acc0[ii] = __builtin_amdgcn_mfma_f32_16x16x32_bf16(a, b0, acc0[ii], 0, 0, 0);
    acc1[ii] = __builtin_amdgcn_mfma_f32_16x16x32_bf16(a, b1, acc1[ii], 0, 0, 0);
  }
}

__global__ __launch_bounds__(NT, 4) void cost_volume_kernel(
    const float* __restrict__ x1, const float* __restrict__ x2,
    float* __restrict__ out, const float* __restrict__ zws) {
  __shared__ unsigned short smem[BUF_USH];  // 51584 B

  const int b = blockIdx.z;
  const int h0 = blockIdx.y * 8;
  const int w0 = blockIdx.x * 16;
  const int t = threadIdx.x;
  const int wid = t >> 6;
  const int hl = wid & 7;
  const int igrp = wid >> 3;
  const int lane = t & 63;
  const int n16 = lane & 15;
  const int quad = lane >> 4;

  const float* x1b = x1 + (size_t)b * 128 * HW;
  const float* x2b = x2 + (size_t)b * 128 * HW;

  // ---- decode this thread's two staging tasks (chunk-invariant parts) ----
  // task ids: tau in [0,2048): tau<512 -> x1 (cp,row,f4); else x2 (tau-512).
  const float* tbase[2];
  int tgoff[2], tlds[2], tcp[2];
  bool tok[2];
#pragma unroll
  for (int s = 0; s < 2; ++s) {
    const int tau = t + s * NT;
    if (tau < 512) {
      const int cp = tau >> 5, rem = tau & 31, row = rem >> 2, f4 = rem & 3;
      tbase[s] = x1b;
      tgoff[s] = (h0 + row) * WW + w0 + f4 * 4;
      tlds[s] = row * A_ROW + f4 * 160 + 2 * cp;
      tcp[s] = cp;
      tok[s] = true;
    } else {
      const int tp = tau - 512;  // 0..1535
      const int cp = tp / 96, rem = tp - cp * 96, row = rem / 6,
                f4 = rem - row * 6;
      const int h2 = h0 - 4 + row;
      const int wg = w0 - 4 + f4 * 4;
      tbase[s] = x2b;
      tgoff[s] = h2 * WW + wg;
      tlds[s] = B_BASE + row * B_ROW + f4 * 160 + 2 * cp;
      tcp[s] = cp;
      tok[s] = ((unsigned)h2 < (unsigned)HH) && ((unsigned)wg <= (unsigned)(WW - 4));
    }
  }

  float4v acc0[5], acc1[5];
#pragma unroll
  for (int ii = 0; ii < 5; ++ii) {
    acc0[ii] = (float4v){0.f, 0.f, 0.f, 0.f};
    acc1[ii] = (float4v){0.f, 0.f, 0.f, 0.f};
  }

  float4 va[2], vb[2];
  // issue loads for chunk 0
#pragma unroll
  for (int s = 0; s < 2; ++s) {
    const float* p = tok[s] ? tbase[s] + (size_t)(2 * tcp[s]) * HW + tgoff[s] : zws;
    const float* q = tok[s] ? p + HW : zws;
    va[s] = *(const float4*)p;
    vb[s] = *(const float4*)q;
  }

  for (int k = 0; k < 4; ++k) {
    if (k > 0) __syncthreads();  // all reads of previous chunk done
    // convert + transpose-write chunk k into LDS (c-pairs packed per b32)
#pragma unroll
    for (int s = 0; s < 2; ++s) {
      const float fa[4] = {va[s].x, va[s].y, va[s].z, va[s].w};
      const float fb[4] = {vb[s].x, vb[s].y, vb[s].z, vb[s].w};
#pragma unroll
      for (int e = 0; e < 4; ++e) {
        const uint32_t w = f2bf(fa[e]) | (f2bf(fb[e]) << 16);
        *(uint32_t*)(&smem[tlds[s] + e * KSTR]) = w;
      }
    }
    __syncthreads();  // LDS visible
    if (k < 3) {      // prefetch chunk k+1 (in flight across compute)
      const int c0 = (k + 1) * 32;
#pragma unroll
      for (int s = 0; s < 2; ++s) {
        const float* p =
            tok[s] ? tbase[s] + (size_t)(c0 + 2 * tcp[s]) * HW + tgoff[s] : zws;
        const float* q = tok[s] ? p + HW : zws;
        va[s] = *(const float4*)p;
        vb[s] = *(const float4*)q;
      }
    }
    if (igrp == 0)
      compute_chunk<5, -4>(smem, hl, n16, quad, acc0, acc1);
    else
      compute_chunk<4, 1>(smem, hl, n16, quad, acc0, acc1);
  }

  // ---- epilogue: scatter D-fragments to LDS scratch, read back coalesced ---
  __syncthreads();  // all compute reads done; reuse smem as fp32 scratch
  float* scratch = (float*)smem;  // 10368 floats = 41472 B
  const float sc = 1.0f / 81.0f;
  const int ni = igrp ? 4 : 5;
  const int i0 = igrp ? 1 : -4;
#pragma unroll 5
  for (int ii = 0; ii < 5; ++ii) {
    if (ii >= ni) break;
    const int iabs = (i0 + ii) + 4;
    const float av0[4] = {acc0[ii].x, acc0[ii].y, acc0[ii].z, acc0[ii].w};
    const float av1[4] = {acc1[ii].x, acc1[ii].y, acc1[ii].z, acc1[ii].w};
#pragma unroll
    for (int reg = 0; reg < 4; ++reg) {
      const int m = quad * 4 + reg;
      // tile0: window col n16 -> j = m + 4 - n16
      {
        const unsigned ja = (unsigned)(m + 4 - n16 + 4);
        if (ja < 9u)
          scratch[hl * 1296 + (iabs * 9 + (int)ja) * 16 + m] = av0[reg] * sc;
      }
      // tile1: window col 16+n16 -> j = m - 12 - n16
      {
        const unsigned ja = (unsigned)(m - 12 - n16 + 4);
        if (ja < 9u)
          scratch[hl * 1296 + (iabs * 9 + (int)ja) * 16 + m] = av1[reg] * sc;
      }
    }
  }
  __syncthreads();

  // coalesced write-out: f -> (kk81, hlx, m4)
  for (int f = t; f < 2592; f += NT) {
    const int m4 = f & 3;
    const int hlx = (f >> 2) & 7;
    const int kk81 = f >> 5;  // iabs*9 + jabs
    const float4 v = *(const float4*)(&scratch[hlx * 1296 + kk81 * 16 + m4 * 4]);
    const int kk = (kk81 + 41) % 81;
    *(float4*)(out + (((size_t)b * DD + kk) * HH + (h0 + hlx)) * WW + w0 +
               m4 * 4) = v;
  }
}

extern "C" void kernel_launch(void* const* d_in, const int* in_sizes, int n_in,
                              void* d_out, int out_size, void* d_ws,
                              size_t ws_size, hipStream_t stream) {
  const float* x1 = (const float*)d_in[0];
  const float* x2 = (const float*)d_in[1];
  float* out = (float*)d_out;

  // zero 256 B of workspace: OOB staging lanes read zeros from here
  hipMemsetAsync(d_ws, 0, 256, stream);

  dim3 grid(WW / 16, HH / 8, 4);  // 16 x 16 x 4 = 1024 blocks
  dim3 block(NT);
  hipLaunchKernelGGL(cost_volume_kernel, grid, block, 0, stream, x1, x2, out,
                     (const float*)d_ws);
}